// Round 2
// baseline (458.403 us; speedup 1.0000x reference)
//
#include <hip/hip_runtime.h>
#include <stdint.h>

constexpr int CB  = 64;     // batches
constexpr int CN  = 2048;   // keypoints per batch
constexpr int CC  = 256;    // channels
constexpr int CNB = 100;    // base classes
constexpr int CNBP = 112;   // padded to 7*16 for MFMA n-tiles
#define EPSF 1e-12f

typedef __attribute__((ext_vector_type(8))) short short8;
typedef __attribute__((ext_vector_type(4))) float floatx4;

__device__ inline short f2bf(float f) {
  union { float f; uint32_t u; } v; v.f = f;
  uint32_t u = v.u;
  uint32_t r = u + 0x7FFFu + ((u >> 16) & 1u);   // RNE (non-NaN inputs)
  return (short)(r >> 16);
}

// ---------------- prep: Wq -> bf16  AND  kn = normalize(bw @ Wk^T + bk) -> bf16 ----------------
// blocks 0..255: Wq cast; blocks 256..367: one m each of kn.
__global__ __launch_bounds__(256) void prep_kernel(
    const float* __restrict__ Wq, short* __restrict__ Wqb,
    const float* __restrict__ bw, const float* __restrict__ Wk,
    const float* __restrict__ bk, short* __restrict__ knb) {
  if (blockIdx.x < 256) {
    int i = blockIdx.x * 256 + threadIdx.x;
    Wqb[i] = f2bf(Wq[i]);
    return;
  }
  const int m = blockIdx.x - 256;   // 0..111
  const int c = threadIdx.x;        // 0..255
  float kv = 0.0f;
  if (m < CNB) {
    const float4* wr = (const float4*)(Wk + (size_t)c * CC);
    const float4* br = (const float4*)(bw + (size_t)m * CC);
    float a0 = 0.f, a1 = 0.f, a2 = 0.f, a3 = 0.f;
    #pragma unroll 4
    for (int j = 0; j < 64; j += 4) {
      float4 w0 = wr[j+0], w1 = wr[j+1], w2 = wr[j+2], w3 = wr[j+3];
      float4 q0 = br[j+0], q1 = br[j+1], q2 = br[j+2], q3 = br[j+3];
      a0 += w0.x*q0.x + w0.y*q0.y + w0.z*q0.z + w0.w*q0.w;
      a1 += w1.x*q1.x + w1.y*q1.y + w1.z*q1.z + w1.w*q1.w;
      a2 += w2.x*q2.x + w2.y*q2.y + w2.z*q2.z + w2.w*q2.w;
      a3 += w3.x*q3.x + w3.y*q3.y + w3.z*q3.z + w3.w*q3.w;
    }
    kv = (a0 + a1) + (a2 + a3) + bk[c];
  }
  float s = kv * kv;
  s += __shfl_xor(s, 1);  s += __shfl_xor(s, 2);  s += __shfl_xor(s, 4);
  s += __shfl_xor(s, 8);  s += __shfl_xor(s, 16); s += __shfl_xor(s, 32);
  __shared__ float red[4];
  const int wv = threadIdx.x >> 6, ln = threadIdx.x & 63;
  if (ln == 0) red[wv] = s;
  __syncthreads();
  const float tot = red[0] + red[1] + red[2] + red[3];
  const float rn = 1.0f / fmaxf(sqrtf(tot), EPSF);
  knb[(size_t)m * CC + c] = (m < CNB) ? f2bf(kv * rn) : (short)0;
}

// ---------------- main: Q = X@Wq^T, S = Q@kn^T * rnorm, softmax, partial sums ----------------
// 2048 blocks (64 b x 32 tiles of 64 rows), 256 threads = 4 waves, 16 rows/wave.
// LDS 33.8 KB/block -> 4 blocks/CU -> 4 waves/EU; launch_bounds(256,4) gives the
// allocator the matching 128-VGPR budget (round-1: default bound -> 52 VGPRs + spills).
// MFMA 16x16x32 bf16 layouts (guide-verified):
//   A: lane holds A[m=lane&15][k=quad*8+j], j=0..7   (8 bf16, contiguous k)
//   B: lane holds B[k=quad*8+j][n=lane&15]           (8 bf16, contiguous k)
//   C/D: lane holds D[m=quad*4+reg][n=lane&15]       (4 f32)
__global__ __launch_bounds__(256, 4) void main_kernel(
    const float* __restrict__ X, const float* __restrict__ mask,
    const short* __restrict__ Wqb, const float* __restrict__ bq,
    const short* __restrict__ knb,
    float* __restrict__ att_sum, float* __restrict__ x_sum, float* __restrict__ mask_sum) {
  const int b    = blockIdx.x >> 5;
  const int tile = blockIdx.x & 31;
  const int n0   = tile * 64;
  const int tid  = threadIdx.x;
  const int wave = tid >> 6;
  const int lane = tid & 63;
  const int quad = lane >> 4;
  const int l16  = lane & 15;
  const int row0 = n0 + wave * 16;

  __shared__ short qlds[4][16][264];   // bf16 Q per wave; pitch 264 -> only 2-way LDS aliasing

  // ---- phase 1: A-frags of X (fp32 -> bf16), fused branch-1 masked column sums ----
  const float mval = mask[(size_t)b * CN + row0 + l16];   // this lane's row mask
  short8 a[8];
  {
    const float* xr = X + ((size_t)b * CN + row0 + l16) * CC + quad * 8;
    #pragma unroll
    for (int kc = 0; kc < 8; ++kc) {
      const float4* p = (const float4*)(xr + kc * 32);
      float4 f0 = p[0], f1 = p[1];
      short8 t;
      t[0] = f2bf(f0.x); t[1] = f2bf(f0.y); t[2] = f2bf(f0.z); t[3] = f2bf(f0.w);
      t[4] = f2bf(f1.x); t[5] = f2bf(f1.y); t[6] = f2bf(f1.z); t[7] = f2bf(f1.w);
      a[kc] = t;
      // branch 1: mask-weighted sum over this wave's 16 rows (the l16 lanes)
      float v[8] = { f0.x*mval, f0.y*mval, f0.z*mval, f0.w*mval,
                     f1.x*mval, f1.y*mval, f1.z*mval, f1.w*mval };
      #pragma unroll
      for (int j = 0; j < 8; ++j) {
        float s = v[j];
        s += __shfl_xor(s, 1); s += __shfl_xor(s, 2);
        s += __shfl_xor(s, 4); s += __shfl_xor(s, 8);
        v[j] = s;
      }
      if (l16 == 0) {
        #pragma unroll
        for (int j = 0; j < 8; ++j)
          atomicAdd(&x_sum[b * CC + quad * 8 + kc * 32 + j], v[j]);
      }
    }
  }
  {   // mask denominator: sum of this wave's 16 row-masks, one atomic per wave
    float ms = mval;
    ms += __shfl_xor(ms, 1); ms += __shfl_xor(ms, 2);
    ms += __shfl_xor(ms, 4); ms += __shfl_xor(ms, 8);
    if (lane == 0) atomicAdd(&mask_sum[b], ms);
  }

  // Q = X @ Wq^T + bq ; stash bf16(Q) to LDS (C-layout -> [row][col]); track row sum-of-squares
  float sumsq[4] = {0.f, 0.f, 0.f, 0.f};
  for (int nt = 0; nt < 16; ++nt) {
    floatx4 acc = {0.f, 0.f, 0.f, 0.f};
    const short* wp = Wqb + (nt * 16 + l16) * CC + quad * 8;   // B[k][n] = Wq[n][k]
    #pragma unroll
    for (int kc = 0; kc < 8; ++kc) {
      short8 bf = *(const short8*)(wp + kc * 32);
      acc = __builtin_amdgcn_mfma_f32_16x16x32_bf16(a[kc], bf, acc, 0, 0, 0);
    }
    const float bqv = bq[nt * 16 + l16];
    #pragma unroll
    for (int r = 0; r < 4; ++r) {
      float q = acc[r] + bqv;
      sumsq[r] += q * q;
      qlds[wave][quad * 4 + r][nt * 16 + l16] = f2bf(q);
    }
  }
  float rnorm[4];
  #pragma unroll
  for (int r = 0; r < 4; ++r) {
    float s = sumsq[r];
    s += __shfl_xor(s, 1); s += __shfl_xor(s, 2);
    s += __shfl_xor(s, 4); s += __shfl_xor(s, 8);
    rnorm[r] = 1.0f / fmaxf(sqrtf(s), EPSF);   // applied to S, not to q (norm commutes)
  }

  // ---- phase 2: A-frags of Q from LDS (layout transpose), S = Q @ kn^T ----
  short8 qa[8];
  #pragma unroll
  for (int kc = 0; kc < 8; ++kc)
    qa[kc] = *(const short8*)&qlds[wave][l16][kc * 32 + quad * 8];

  floatx4 sacc[7];
  #pragma unroll
  for (int nt = 0; nt < 7; ++nt) {
    floatx4 acc = {0.f, 0.f, 0.f, 0.f};
    const short* kp = knb + (nt * 16 + l16) * CC + quad * 8;   // B[k][n] = kn[n][k]
    #pragma unroll
    for (int kc = 0; kc < 8; ++kc) {
      short8 bf = *(const short8*)(kp + kc * 32);
      acc = __builtin_amdgcn_mfma_f32_16x16x32_bf16(qa[kc], bf, acc, 0, 0, 0);
    }
    sacc[nt] = acc;
  }

  // ---- softmax over m (|s|<=1 so no max-subtraction needed) + masked accumulation ----
  float mw[4];
  #pragma unroll
  for (int r = 0; r < 4; ++r)
    mw[r] = __shfl(mval, quad * 4 + r, 16);   // mask of row quad*4+r, from the l16 lanes

  const bool v6 = (l16 < 4);               // tile 6 covers m=96..111; valid iff m<100
  float p[7][4];
  float denom[4] = {0.f, 0.f, 0.f, 0.f};
  #pragma unroll
  for (int nt = 0; nt < 7; ++nt) {
    const bool v = (nt < 6) || v6;
    #pragma unroll
    for (int r = 0; r < 4; ++r) {
      float e = v ? __expf(sacc[nt][r] * rnorm[r]) : 0.0f;
      p[nt][r] = e;
      denom[r] += e;
    }
  }
  float wr[4];
  #pragma unroll
  for (int r = 0; r < 4; ++r) {
    float s = denom[r];
    s += __shfl_xor(s, 1); s += __shfl_xor(s, 2);
    s += __shfl_xor(s, 4); s += __shfl_xor(s, 8);
    wr[r] = mw[r] / s;                      // fold mask weight and 1/denom
  }
  #pragma unroll
  for (int nt = 0; nt < 7; ++nt) {
    float contrib = p[nt][0] * wr[0] + p[nt][1] * wr[1] + p[nt][2] * wr[2] + p[nt][3] * wr[3];
    contrib += __shfl_xor(contrib, 16);
    contrib += __shfl_xor(contrib, 32);     // sum the wave's 16 rows
    if (quad == 0)
      atomicAdd(&att_sum[b * CNBP + nt * 16 + l16], contrib);
  }
}

// ---------------- final combine ----------------
__global__ __launch_bounds__(256) void final_kernel(
    const float* __restrict__ bw, const float* __restrict__ w_avg,
    const float* __restrict__ w_att,
    const float* __restrict__ att_sum, const float* __restrict__ x_sum,
    const float* __restrict__ mask_sum, float* __restrict__ out) {
  const int b = blockIdx.x, c = threadIdx.x;
  const float rd  = 1.0f / fmaxf(mask_sum[b], EPSF);
  const float wn1 = x_sum[b * CC + c] * rd * w_avg[c];
  float acc = 0.0f;
  #pragma unroll 10
  for (int m = 0; m < CNB; ++m)
    acc += att_sum[b * CNBP + m] * bw[(size_t)m * CC + c];
  const float wn2 = acc * rd;
  out[b * CC + c] = (wn1 + wn2 * w_att[c]) * 0.5f;
}

extern "C" void kernel_launch(void* const* d_in, const int* in_sizes, int n_in,
                              void* d_out, int out_size, void* d_ws, size_t ws_size,
                              hipStream_t stream) {
  const float* bw    = (const float*)d_in[0];
  const float* X     = (const float*)d_in[1];
  const float* mask  = (const float*)d_in[2];
  const float* Wq    = (const float*)d_in[3];
  const float* bq    = (const float*)d_in[4];
  const float* Wk    = (const float*)d_in[5];
  const float* bk    = (const float*)d_in[6];
  const float* w_avg = (const float*)d_in[7];
  const float* w_att = (const float*)d_in[8];
  float* out = (float*)d_out;

  char* ws = (char*)d_ws;
  short* Wqb     = (short*)(ws + 0);        // 131072 B
  short* knb     = (short*)(ws + 131072);   //  57344 B
  float* att_sum = (float*)(ws + 188416);   //  28672 B (64 x 112)
  float* x_sum   = (float*)(ws + 217088);   //  65536 B (64 x 256)
  float* msum    = (float*)(ws + 282624);   //    256 B (64)

  // zero the accumulators (ws is poisoned each call); region is contiguous
  hipMemsetAsync(ws + 188416, 0, 28672 + 65536 + 256, stream);

  prep_kernel<<<368, 256, 0, stream>>>(Wq, Wqb, bw, Wk, bk, knb);
  main_kernel<<<CB * (CN / 64), 256, 0, stream>>>(X, mask, Wqb, bq, knb, att_sum, x_sum, msum);
  final_kernel<<<CB, CC, 0, stream>>>(bw, w_avg, w_att, att_sum, x_sum, msum, out);
}

// Round 3
// 368.059 us; speedup vs baseline: 1.2455x; 1.2455x over previous
//
#include <hip/hip_runtime.h>
#include <stdint.h>

constexpr int CB  = 64;     // batches
constexpr int CN  = 2048;   // keypoints per batch
constexpr int CC  = 256;    // channels
constexpr int CNB = 100;    // base classes
constexpr int CNBP = 112;   // padded to 7*16 for MFMA n-tiles
#define EPSF 1e-12f

typedef __attribute__((ext_vector_type(8))) short short8;
typedef __attribute__((ext_vector_type(4))) float floatx4;

__device__ inline short f2bf(float f) {
  union { float f; uint32_t u; } v; v.f = f;
  uint32_t u = v.u;
  uint32_t r = u + 0x7FFFu + ((u >> 16) & 1u);   // RNE (non-NaN inputs)
  return (short)(r >> 16);
}

// ---------------- prep: Wq -> bf16  AND  kn = normalize(bw @ Wk^T + bk) -> bf16 ----------------
// blocks 0..255: Wq cast; blocks 256..367: one m each of kn.
__global__ __launch_bounds__(256) void prep_kernel(
    const float* __restrict__ Wq, short* __restrict__ Wqb,
    const float* __restrict__ bw, const float* __restrict__ Wk,
    const float* __restrict__ bk, short* __restrict__ knb) {
  if (blockIdx.x < 256) {
    int i = blockIdx.x * 256 + threadIdx.x;
    Wqb[i] = f2bf(Wq[i]);
    return;
  }
  const int m = blockIdx.x - 256;   // 0..111
  const int c = threadIdx.x;        // 0..255
  float kv = 0.0f;
  if (m < CNB) {
    const float4* wr = (const float4*)(Wk + (size_t)c * CC);
    const float4* br = (const float4*)(bw + (size_t)m * CC);
    float a0 = 0.f, a1 = 0.f, a2 = 0.f, a3 = 0.f;
    #pragma unroll 4
    for (int j = 0; j < 64; j += 4) {
      float4 w0 = wr[j+0], w1 = wr[j+1], w2 = wr[j+2], w3 = wr[j+3];
      float4 q0 = br[j+0], q1 = br[j+1], q2 = br[j+2], q3 = br[j+3];
      a0 += w0.x*q0.x + w0.y*q0.y + w0.z*q0.z + w0.w*q0.w;
      a1 += w1.x*q1.x + w1.y*q1.y + w1.z*q1.z + w1.w*q1.w;
      a2 += w2.x*q2.x + w2.y*q2.y + w2.z*q2.z + w2.w*q2.w;
      a3 += w3.x*q3.x + w3.y*q3.y + w3.z*q3.z + w3.w*q3.w;
    }
    kv = (a0 + a1) + (a2 + a3) + bk[c];
  }
  float s = kv * kv;
  s += __shfl_xor(s, 1);  s += __shfl_xor(s, 2);  s += __shfl_xor(s, 4);
  s += __shfl_xor(s, 8);  s += __shfl_xor(s, 16); s += __shfl_xor(s, 32);
  __shared__ float red[4];
  const int wv = threadIdx.x >> 6, ln = threadIdx.x & 63;
  if (ln == 0) red[wv] = s;
  __syncthreads();
  const float tot = red[0] + red[1] + red[2] + red[3];
  const float rn = 1.0f / fmaxf(sqrtf(tot), EPSF);
  knb[(size_t)m * CC + c] = (m < CNB) ? f2bf(kv * rn) : (short)0;
}

// ---------------- main: Q = X@Wq^T, S = Q@kn^T * rnorm, softmax, partial sums ----------------
// 2048 blocks (64 b x 32 tiles of 64 rows), 256 threads = 4 waves, 16 rows/wave.
// launch_bounds(256,3): ~170-VGPR cap. LDS (33.8 KB) already limits to 4 blocks/CU,
// so the looser reg class costs little occupancy but stops the 64-reg spill/remat
// behavior seen in rounds 1-2 (round 2: WRITE_SIZE 104 MB of scratch spills).
// MFMA 16x16x32 bf16 layouts (guide-verified):
//   A: lane holds A[m=lane&15][k=quad*8+j], j=0..7   (8 bf16, contiguous k)
//   B: lane holds B[k=quad*8+j][n=lane&15]           (8 bf16, contiguous k)
//   C/D: lane holds D[m=quad*4+reg][n=lane&15]       (4 f32)
__global__ __launch_bounds__(256, 3) void main_kernel(
    const float* __restrict__ X, const float* __restrict__ mask,
    const short* __restrict__ Wqb, const float* __restrict__ bq,
    const short* __restrict__ knb,
    float* __restrict__ att_sum, float* __restrict__ x_sum, float* __restrict__ mask_sum) {
  const int b    = blockIdx.x >> 5;
  const int tile = blockIdx.x & 31;
  const int n0   = tile * 64;
  const int tid  = threadIdx.x;
  const int wave = tid >> 6;
  const int lane = tid & 63;
  const int quad = lane >> 4;
  const int l16  = lane & 15;
  const int row0 = n0 + wave * 16;

  __shared__ short qlds[4][16][264];   // bf16 Q per wave; pitch 264 -> only 2-way LDS aliasing

  // ---- phase 1: A-frags of X (fp32 -> bf16) ----
  short8 a[8];
  {
    const float* xr = X + ((size_t)b * CN + row0 + l16) * CC + quad * 8;
    #pragma unroll
    for (int kc = 0; kc < 8; ++kc) {
      const float4* p = (const float4*)(xr + kc * 32);
      float4 f0 = p[0], f1 = p[1];
      short8 t;
      t[0] = f2bf(f0.x); t[1] = f2bf(f0.y); t[2] = f2bf(f0.z); t[3] = f2bf(f0.w);
      t[4] = f2bf(f1.x); t[5] = f2bf(f1.y); t[6] = f2bf(f1.z); t[7] = f2bf(f1.w);
      a[kc] = t;
    }
  }
  // Q = X @ Wq^T + bq ; stash bf16(Q) to LDS (C-layout -> [row][col]); track row sum-of-squares
  float sumsq[4] = {0.f, 0.f, 0.f, 0.f};
  for (int nt = 0; nt < 16; ++nt) {
    floatx4 acc = {0.f, 0.f, 0.f, 0.f};
    const short* wp = Wqb + (nt * 16 + l16) * CC + quad * 8;   // B[k][n] = Wq[n][k]
    #pragma unroll
    for (int kc = 0; kc < 8; ++kc) {
      short8 bf = *(const short8*)(wp + kc * 32);
      acc = __builtin_amdgcn_mfma_f32_16x16x32_bf16(a[kc], bf, acc, 0, 0, 0);
    }
    const float bqv = bq[nt * 16 + l16];
    #pragma unroll
    for (int r = 0; r < 4; ++r) {
      float q = acc[r] + bqv;
      sumsq[r] += q * q;
      qlds[wave][quad * 4 + r][nt * 16 + l16] = f2bf(q);
    }
  }
  float rnorm[4];
  #pragma unroll
  for (int r = 0; r < 4; ++r) {
    float s = sumsq[r];
    s += __shfl_xor(s, 1); s += __shfl_xor(s, 2);
    s += __shfl_xor(s, 4); s += __shfl_xor(s, 8);
    rnorm[r] = 1.0f / fmaxf(sqrtf(s), EPSF);   // applied to S, not to q (norm commutes)
  }

  // ---- phase 2: A-frags of Q from LDS (layout transpose), S = Q @ kn^T ----
  short8 qa[8];
  #pragma unroll
  for (int kc = 0; kc < 8; ++kc)
    qa[kc] = *(const short8*)&qlds[wave][l16][kc * 32 + quad * 8];

  floatx4 sacc[7];
  #pragma unroll
  for (int nt = 0; nt < 7; ++nt) {
    floatx4 acc = {0.f, 0.f, 0.f, 0.f};
    const short* kp = knb + (nt * 16 + l16) * CC + quad * 8;   // B[k][n] = kn[n][k]
    #pragma unroll
    for (int kc = 0; kc < 8; ++kc) {
      short8 bf = *(const short8*)(kp + kc * 32);
      acc = __builtin_amdgcn_mfma_f32_16x16x32_bf16(qa[kc], bf, acc, 0, 0, 0);
    }
    sacc[nt] = acc;
  }

  // ---- softmax over m: two passes over sacc (recompute exp; saves 28 live VGPRs
  // vs holding p[7][4]). |s|<=1 so no max-subtraction needed. ----
  float mw[4];
  #pragma unroll
  for (int r = 0; r < 4; ++r)
    mw[r] = mask[(size_t)b * CN + row0 + quad * 4 + r];

  const bool v6 = (l16 < 4);               // tile 6 covers m=96..111; valid iff m<100
  float denom[4] = {0.f, 0.f, 0.f, 0.f};
  #pragma unroll
  for (int nt = 0; nt < 7; ++nt) {
    const bool v = (nt < 6) || v6;
    #pragma unroll
    for (int r = 0; r < 4; ++r)
      denom[r] += v ? __expf(sacc[nt][r] * rnorm[r]) : 0.0f;
  }
  float wr[4];
  #pragma unroll
  for (int r = 0; r < 4; ++r) {
    float s = denom[r];
    s += __shfl_xor(s, 1); s += __shfl_xor(s, 2);
    s += __shfl_xor(s, 4); s += __shfl_xor(s, 8);
    wr[r] = mw[r] / s;                      // fold mask weight and 1/denom
  }
  #pragma unroll
  for (int nt = 0; nt < 7; ++nt) {
    const bool v = (nt < 6) || v6;
    float contrib = 0.0f;
    #pragma unroll
    for (int r = 0; r < 4; ++r) {
      float e = v ? __expf(sacc[nt][r] * rnorm[r]) : 0.0f;
      contrib += e * wr[r];
    }
    contrib += __shfl_xor(contrib, 16);
    contrib += __shfl_xor(contrib, 32);     // sum the wave's 16 rows
    if (quad == 0)
      atomicAdd(&att_sum[b * CNBP + nt * 16 + l16], contrib);
  }

  // ---- branch 1 (fp32): masked column sums over the block's 64 rows ----
  // Re-reads the tile just streamed in phase 1 (L1/L2-hot); ~3 live regs.
  {
    float acc = 0.0f;
    const float* xp = X + ((size_t)b * CN + n0) * CC + tid;
    const float* mp = mask + (size_t)b * CN + n0;
    #pragma unroll 8
    for (int r = 0; r < 64; ++r)
      acc += mp[r] * xp[(size_t)r * CC];    // coalesced across threads
    atomicAdd(&x_sum[b * CC + tid], acc);
  }
  if (wave == 0) {
    float mv = mask[(size_t)b * CN + n0 + lane];
    mv += __shfl_xor(mv, 1); mv += __shfl_xor(mv, 2); mv += __shfl_xor(mv, 4);
    mv += __shfl_xor(mv, 8); mv += __shfl_xor(mv, 16); mv += __shfl_xor(mv, 32);
    if (lane == 0) atomicAdd(&mask_sum[b], mv);
  }
}

// ---------------- final combine ----------------
__global__ __launch_bounds__(256) void final_kernel(
    const float* __restrict__ bw, const float* __restrict__ w_avg,
    const float* __restrict__ w_att,
    const float* __restrict__ att_sum, const float* __restrict__ x_sum,
    const float* __restrict__ mask_sum, float* __restrict__ out) {
  const int b = blockIdx.x, c = threadIdx.x;
  const float rd  = 1.0f / fmaxf(mask_sum[b], EPSF);
  const float wn1 = x_sum[b * CC + c] * rd * w_avg[c];
  float acc = 0.0f;
  #pragma unroll 10
  for (int m = 0; m < CNB; ++m)
    acc += att_sum[b * CNBP + m] * bw[(size_t)m * CC + c];
  const float wn2 = acc * rd;
  out[b * CC + c] = (wn1 + wn2 * w_att[c]) * 0.5f;
}

extern "C" void kernel_launch(void* const* d_in, const int* in_sizes, int n_in,
                              void* d_out, int out_size, void* d_ws, size_t ws_size,
                              hipStream_t stream) {
  const float* bw    = (const float*)d_in[0];
  const float* X     = (const float*)d_in[1];
  const float* mask  = (const float*)d_in[2];
  const float* Wq    = (const float*)d_in[3];
  const float* bq    = (const float*)d_in[4];
  const float* Wk    = (const float*)d_in[5];
  const float* bk    = (const float*)d_in[6];
  const float* w_avg = (const float*)d_in[7];
  const float* w_att = (const float*)d_in[8];
  float* out = (float*)d_out;

  char* ws = (char*)d_ws;
  short* Wqb     = (short*)(ws + 0);        // 131072 B
  short* knb     = (short*)(ws + 131072);   //  57344 B
  float* att_sum = (float*)(ws + 188416);   //  28672 B (64 x 112)
  float* x_sum   = (float*)(ws + 217088);   //  65536 B (64 x 256)
  float* msum    = (float*)(ws + 282624);   //    256 B (64)

  // zero the accumulators (ws is poisoned each call); region is contiguous
  hipMemsetAsync(ws + 188416, 0, 28672 + 65536 + 256, stream);

  prep_kernel<<<368, 256, 0, stream>>>(Wq, Wqb, bw, Wk, bk, knb);
  main_kernel<<<CB * (CN / 64), 256, 0, stream>>>(X, mask, Wqb, bq, knb, att_sum, x_sum, msum);
  final_kernel<<<CB, CC, 0, stream>>>(bw, w_avg, w_att, att_sum, x_sum, msum, out);
}

// Round 4
// 286.020 us; speedup vs baseline: 1.6027x; 1.2868x over previous
//
#include <hip/hip_runtime.h>
#include <stdint.h>

constexpr int CB  = 64;     // batches
constexpr int CN  = 2048;   // keypoints per batch
constexpr int CC  = 256;    // channels
constexpr int CNB = 100;    // base classes
constexpr int CNBP = 112;   // padded to 7*16 for MFMA n-tiles
#define EPSF 1e-12f

typedef __attribute__((ext_vector_type(8))) short short8;
typedef __attribute__((ext_vector_type(4))) float floatx4;

typedef const __attribute__((address_space(1))) void* gas_ptr;
typedef __attribute__((address_space(3))) void* las_ptr;

__device__ inline short f2bf(float f) {
  union { float f; uint32_t u; } v; v.f = f;
  uint32_t u = v.u;
  uint32_t r = u + 0x7FFFu + ((u >> 16) & 1u);   // RNE (non-NaN inputs)
  return (short)(r >> 16);
}

// ---------------- prep ----------------
// blocks 0..255: Wq -> bf16 cast.
// blocks 256..367 (one m each): kn_m = normalize(bw_m @ Wk^T + bk)  (fp32, in LDS),
//                               then KW_m = kn_m @ Wq -> bf16 (KW trick: S = X @ KW^T).
__global__ __launch_bounds__(256) void prep_kernel(
    const float* __restrict__ Wq, short* __restrict__ Wqb,
    const float* __restrict__ bw, const float* __restrict__ Wk,
    const float* __restrict__ bk, short* __restrict__ KWb) {
  if (blockIdx.x < 256) {
    int i = blockIdx.x * 256 + threadIdx.x;
    Wqb[i] = f2bf(Wq[i]);
    return;
  }
  const int m = blockIdx.x - 256;   // 0..111
  const int c = threadIdx.x;        // 0..255
  __shared__ float knm[CC];
  __shared__ float red[4];

  float kv = 0.0f;
  if (m < CNB) {
    const float4* wr = (const float4*)(Wk + (size_t)c * CC);
    const float4* br = (const float4*)(bw + (size_t)m * CC);
    float a0 = 0.f, a1 = 0.f, a2 = 0.f, a3 = 0.f;
    #pragma unroll 4
    for (int j = 0; j < 64; j += 4) {
      float4 w0 = wr[j+0], w1 = wr[j+1], w2 = wr[j+2], w3 = wr[j+3];
      float4 q0 = br[j+0], q1 = br[j+1], q2 = br[j+2], q3 = br[j+3];
      a0 += w0.x*q0.x + w0.y*q0.y + w0.z*q0.z + w0.w*q0.w;
      a1 += w1.x*q1.x + w1.y*q1.y + w1.z*q1.z + w1.w*q1.w;
      a2 += w2.x*q2.x + w2.y*q2.y + w2.z*q2.z + w2.w*q2.w;
      a3 += w3.x*q3.x + w3.y*q3.y + w3.z*q3.z + w3.w*q3.w;
    }
    kv = (a0 + a1) + (a2 + a3) + bk[c];
  }
  float s = kv * kv;
  s += __shfl_xor(s, 1);  s += __shfl_xor(s, 2);  s += __shfl_xor(s, 4);
  s += __shfl_xor(s, 8);  s += __shfl_xor(s, 16); s += __shfl_xor(s, 32);
  const int wv = threadIdx.x >> 6, ln = threadIdx.x & 63;
  if (ln == 0) red[wv] = s;
  __syncthreads();
  const float tot = red[0] + red[1] + red[2] + red[3];
  const float rn = 1.0f / fmaxf(sqrtf(tot), EPSF);
  knm[c] = kv * rn;                 // zero rows for m>=100 (kv==0)
  __syncthreads();
  // KW[m][c] = sum_cc knm[cc] * Wq[cc][c]; coalesced over c, Wq L2-hot across blocks
  float acc0 = 0.f, acc1 = 0.f, acc2 = 0.f, acc3 = 0.f;
  const float* wq = Wq + c;
  #pragma unroll 4
  for (int cc = 0; cc < CC; cc += 4) {
    acc0 += knm[cc+0] * wq[(size_t)(cc+0) * CC];
    acc1 += knm[cc+1] * wq[(size_t)(cc+1) * CC];
    acc2 += knm[cc+2] * wq[(size_t)(cc+2) * CC];
    acc3 += knm[cc+3] * wq[(size_t)(cc+3) * CC];
  }
  KWb[(size_t)m * CC + c] = (m < CNB) ? f2bf((acc0 + acc1) + (acc2 + acc3)) : (short)0;
}

// ---------------- main ----------------
// 2048 blocks (64 b x 32 tiles of 64 rows), 256 threads = 4 waves, 16 rows/wave.
// Tile stream: 16 Wq n-tiles (Q phase, sumsq only) + 7 KW n-tiles (S phase) —
// both consume the SAME X A-frags held in registers (KW trick removes the Q
// transpose). B tiles (8 KB = 16 rows x 256 bf16, contiguous) are staged
// cooperatively into double-buffered LDS via global_load_lds (wave-uniform
// base + lane*16B); ds_read_b128 at lane*16 stride is conflict-free and the
// load->MFMA chain is ~40cyc LDS instead of ~200cyc L2 (round-3 bottleneck).
// MFMA 16x16x32 bf16 layouts (guide-verified):
//   A: lane holds A[m=lane&15][k=quad*8+j], j=0..7
//   B: lane holds B[k=quad*8+j][n=lane&15]
//   C/D: lane holds D[m=quad*4+r][n=lane&15]
__global__ __launch_bounds__(256, 3) void main_kernel(
    const float* __restrict__ X, const float* __restrict__ mask,
    const short* __restrict__ Wqb, const float* __restrict__ bq,
    const short* __restrict__ KWb,
    float* __restrict__ att_sum, float* __restrict__ x_sum, float* __restrict__ mask_sum) {
  const int b    = blockIdx.x >> 5;
  const int tile = blockIdx.x & 31;
  const int n0   = tile * 64;
  const int tid  = threadIdx.x;
  const int wave = tid >> 6;
  const int lane = tid & 63;
  const int quad = lane >> 4;
  const int l16  = lane & 15;
  const int row0 = n0 + wave * 16;

  __shared__ short btile[2][4096];   // 2 x 8 KB B-tile double buffer

  // stage one 8KB tile: 8 chunks of 1KB; wave w stages chunks 2w, 2w+1.
  // chunk c holds, at lane*16B, global (row l16, cols c*32+quad*8 .. +7) —
  // exactly the B-frag this lane reads at kc=c.
  #define STAGE(buf, src)                                                        \
    {                                                                            \
      const char* _sb = (const char*)(src);                                      \
      _Pragma("unroll")                                                          \
      for (int _i = 0; _i < 2; ++_i) {                                           \
        const int _c = wave * 2 + _i;                                            \
        __builtin_amdgcn_global_load_lds(                                        \
            (gas_ptr)(_sb + l16 * 512 + _c * 64 + quad * 16),                    \
            (las_ptr)&btile[buf][_c * 512], 16, 0, 0);                           \
      }                                                                          \
    }

  STAGE(0, Wqb)   // tile 0 in flight while we fetch X

  // ---- A-frags of X (fp32 -> bf16), held for BOTH matmul phases ----
  short8 a[8];
  {
    const float* xr = X + ((size_t)b * CN + row0 + l16) * CC + quad * 8;
    #pragma unroll
    for (int kc = 0; kc < 8; ++kc) {
      const float4* p = (const float4*)(xr + kc * 32);
      float4 f0 = p[0], f1 = p[1];
      short8 t;
      t[0] = f2bf(f0.x); t[1] = f2bf(f0.y); t[2] = f2bf(f0.z); t[3] = f2bf(f0.w);
      t[4] = f2bf(f1.x); t[5] = f2bf(f1.y); t[6] = f2bf(f1.z); t[7] = f2bf(f1.w);
      a[kc] = t;
    }
  }

  // ---- Q phase: 16 tiles, accumulate row sum-of-squares only ----
  float sumsq[4] = {0.f, 0.f, 0.f, 0.f};
  for (int t = 0; t < 16; ++t) {
    const int cur = t & 1;
    __syncthreads();                       // staging(cur) drained; reads of cur^1 done
    if (t < 15)      STAGE(cur ^ 1, Wqb + (t + 1) * 4096)
    else             STAGE(cur ^ 1, KWb)   // first S tile
    floatx4 acc = {0.f, 0.f, 0.f, 0.f};
    const short* bp = &btile[cur][lane * 8];
    #pragma unroll
    for (int kc = 0; kc < 8; ++kc) {
      short8 bf = *(const short8*)(bp + kc * 512);
      acc = __builtin_amdgcn_mfma_f32_16x16x32_bf16(a[kc], bf, acc, 0, 0, 0);
    }
    const float bqv = bq[t * 16 + l16];
    #pragma unroll
    for (int r = 0; r < 4; ++r) {
      float q = acc[r] + bqv;
      sumsq[r] += q * q;
    }
  }

  // ---- S phase: 7 tiles into sacc (unrolled -> static indexing, no scratch) ----
  floatx4 sacc[7];
  #pragma unroll
  for (int nt = 0; nt < 7; ++nt) {
    const int cur = (16 + nt) & 1;
    __syncthreads();
    if (nt < 6) STAGE(cur ^ 1, KWb + (nt + 1) * 4096)
    floatx4 acc = {0.f, 0.f, 0.f, 0.f};
    const short* bp = &btile[cur][lane * 8];
    #pragma unroll
    for (int kc = 0; kc < 8; ++kc) {
      short8 bf = *(const short8*)(bp + kc * 512);
      acc = __builtin_amdgcn_mfma_f32_16x16x32_bf16(a[kc], bf, acc, 0, 0, 0);
    }
    sacc[nt] = acc;
  }

  // ---- rnorm per row (norm commutes: applied to S logits) ----
  float rnorm[4];
  #pragma unroll
  for (int r = 0; r < 4; ++r) {
    float s = sumsq[r];
    s += __shfl_xor(s, 1); s += __shfl_xor(s, 2);
    s += __shfl_xor(s, 4); s += __shfl_xor(s, 8);
    rnorm[r] = 1.0f / fmaxf(sqrtf(s), EPSF);
  }

  // ---- softmax over m: two passes over sacc (recompute exp, saves 28 VGPRs).
  // |logit|<=1 (cosine), no max-subtraction needed. ----
  float mw[4];
  #pragma unroll
  for (int r = 0; r < 4; ++r)
    mw[r] = mask[(size_t)b * CN + row0 + quad * 4 + r];

  const bool v6 = (l16 < 4);               // tile 6 covers m=96..111; valid iff m<100
  float denom[4] = {0.f, 0.f, 0.f, 0.f};
  #pragma unroll
  for (int nt = 0; nt < 7; ++nt) {
    const bool v = (nt < 6) || v6;
    #pragma unroll
    for (int r = 0; r < 4; ++r)
      denom[r] += v ? __expf(sacc[nt][r] * rnorm[r]) : 0.0f;
  }
  float wr[4];
  #pragma unroll
  for (int r = 0; r < 4; ++r) {
    float s = denom[r];
    s += __shfl_xor(s, 1); s += __shfl_xor(s, 2);
    s += __shfl_xor(s, 4); s += __shfl_xor(s, 8);
    wr[r] = mw[r] / s;                      // fold mask weight and 1/denom
  }
  #pragma unroll
  for (int nt = 0; nt < 7; ++nt) {
    const bool v = (nt < 6) || v6;
    float contrib = 0.0f;
    #pragma unroll
    for (int r = 0; r < 4; ++r) {
      float e = v ? __expf(sacc[nt][r] * rnorm[r]) : 0.0f;
      contrib += e * wr[r];
    }
    contrib += __shfl_xor(contrib, 16);
    contrib += __shfl_xor(contrib, 32);     // sum the wave's 16 rows
    if (quad == 0)
      atomicAdd(&att_sum[b * CNBP + nt * 16 + l16], contrib);
  }

  // ---- branch 1 (fp32): masked column sums over the block's 64 rows (L2-hot) ----
  {
    float acc = 0.0f;
    const float* xp = X + ((size_t)b * CN + n0) * CC + tid;
    const float* mp = mask + (size_t)b * CN + n0;
    #pragma unroll 8
    for (int r = 0; r < 64; ++r)
      acc += mp[r] * xp[(size_t)r * CC];    // coalesced across threads
    atomicAdd(&x_sum[b * CC + tid], acc);
  }
  if (wave == 0) {
    float mv = mask[(size_t)b * CN + n0 + lane];
    mv += __shfl_xor(mv, 1); mv += __shfl_xor(mv, 2); mv += __shfl_xor(mv, 4);
    mv += __shfl_xor(mv, 8); mv += __shfl_xor(mv, 16); mv += __shfl_xor(mv, 32);
    if (lane == 0) atomicAdd(&mask_sum[b], mv);
  }
  #undef STAGE
}

// ---------------- final combine ----------------
__global__ __launch_bounds__(256) void final_kernel(
    const float* __restrict__ bw, const float* __restrict__ w_avg,
    const float* __restrict__ w_att,
    const float* __restrict__ att_sum, const float* __restrict__ x_sum,
    const float* __restrict__ mask_sum, float* __restrict__ out) {
  const int b = blockIdx.x, c = threadIdx.x;
  const float rd  = 1.0f / fmaxf(mask_sum[b], EPSF);
  const float wn1 = x_sum[b * CC + c] * rd * w_avg[c];
  float acc = 0.0f;
  #pragma unroll 10
  for (int m = 0; m < CNB; ++m)
    acc += att_sum[b * CNBP + m] * bw[(size_t)m * CC + c];
  const float wn2 = acc * rd;
  out[b * CC + c] = (wn1 + wn2 * w_att[c]) * 0.5f;
}

extern "C" void kernel_launch(void* const* d_in, const int* in_sizes, int n_in,
                              void* d_out, int out_size, void* d_ws, size_t ws_size,
                              hipStream_t stream) {
  const float* bw    = (const float*)d_in[0];
  const float* X     = (const float*)d_in[1];
  const float* mask  = (const float*)d_in[2];
  const float* Wq    = (const float*)d_in[3];
  const float* bq    = (const float*)d_in[4];
  const float* Wk    = (const float*)d_in[5];
  const float* bk    = (const float*)d_in[6];
  const float* w_avg = (const float*)d_in[7];
  const float* w_att = (const float*)d_in[8];
  float* out = (float*)d_out;

  char* ws = (char*)d_ws;
  short* Wqb     = (short*)(ws + 0);        // 131072 B
  short* KWb     = (short*)(ws + 131072);   //  57344 B (112 x 256 bf16)
  float* att_sum = (float*)(ws + 188416);   //  28672 B (64 x 112)
  float* x_sum   = (float*)(ws + 217088);   //  65536 B (64 x 256)
  float* msum    = (float*)(ws + 282624);   //    256 B (64)

  // zero the accumulators (ws is poisoned each call); region is contiguous
  hipMemsetAsync(ws + 188416, 0, 28672 + 65536 + 256, stream);

  prep_kernel<<<368, 256, 0, stream>>>(Wq, Wqb, bw, Wk, bk, KWb);
  main_kernel<<<CB * (CN / 64), 256, 0, stream>>>(X, mask, Wqb, bq, KWb, att_sum, x_sum, msum);
  final_kernel<<<CB, CC, 0, stream>>>(bw, w_avg, w_att, att_sum, x_sum, msum, out);
}

// Round 5
// 256.807 us; speedup vs baseline: 1.7850x; 1.1138x over previous
//
#include <hip/hip_runtime.h>
#include <stdint.h>

constexpr int CB  = 64;     // batches
constexpr int CN  = 2048;   // keypoints per batch
constexpr int CC  = 256;    // channels
constexpr int CNB = 100;    // base classes
constexpr int CNBP = 112;   // padded to 7*16 for MFMA n-tiles
#define EPSF 1e-12f

typedef __attribute__((ext_vector_type(8))) short short8;
typedef __attribute__((ext_vector_type(4))) float floatx4;
typedef __attribute__((ext_vector_type(2))) long long2v;

typedef const __attribute__((address_space(1))) void* gas_ptr;
typedef __attribute__((address_space(3))) void* las_ptr;

__device__ inline short f2bf(float f) {
  union { float f; uint32_t u; } v; v.f = f;
  uint32_t u = v.u;
  uint32_t r = u + 0x7FFFu + ((u >> 16) & 1u);   // RNE (non-NaN inputs)
  return (short)(r >> 16);
}

// =========================== prep A ===========================
// grid 256 x 256: block n, thread k.
//  - WkT[k][n] = Wk[n][k]  (transpose for coalesced prepB reads)
//  - Wq8: fp8(e4m3) of Wq in MFMA-B *tiled* layout so main can stage it into
//    LDS with a pure linear copy and read frags at lane*16 (conflict-free).
//    Element Wq[n][k] -> tile t=n>>4, frag lane=quad*16+l16 (l16=n&15,
//    quad=(k>>3)&3), kc=k>>5, j=k&7:
//    byte = t*4096 + (kc>>1)*1024 + lane*16 + (kc&1)*8 + j
__global__ __launch_bounds__(256) void prepA_kernel(
    const float* __restrict__ Wq, const float* __restrict__ Wk,
    unsigned char* __restrict__ Wq8, float* __restrict__ WkT) {
  const int n = blockIdx.x, k = threadIdx.x;
  WkT[(size_t)k * CC + n] = Wk[(size_t)n * CC + k];
  if (k < 128) {
    const int k0 = 2 * k;
    const float w0 = Wq[(size_t)n * CC + k0];
    const float w1 = Wq[(size_t)n * CC + k0 + 1];
    // both A and B sides use the same (even,odd) pack convention, so any
    // byte-order quirk of cvt_pk cancels in the MFMA dot product
    int pk = __builtin_amdgcn_cvt_pk_fp8_f32(w0, w1, 0, false);
    const int t = n >> 4, l16 = n & 15, kc = k0 >> 5, quad = (k0 >> 3) & 3, j = k0 & 7;
    const int lane = quad * 16 + l16;
    const size_t byte = (size_t)t * 4096 + (kc >> 1) * 1024 + lane * 16 + (kc & 1) * 8 + j;
    *(uint16_t*)(Wq8 + byte) = (uint16_t)(pk & 0xFFFF);
  }
}

// =========================== prep B ===========================
// grid 112 x 256: block m, thread c.
// kn_m = normalize(bw_m @ Wk^T + bk); KW_m = kn_m @ Wq  (KW trick: S = X@KW^T).
// KWt: bf16 KW in MFMA-B tiled layout (16B per lane-frag):
//   element KW[m][c] -> nt=m>>4, l16=m&15, kc=c>>5, quad=(c>>3)&3, j=c&7,
//   lane=quad*16+l16: byte = nt*8192 + kc*1024 + lane*16 + j*2
__global__ __launch_bounds__(256) void prepB_kernel(
    const float* __restrict__ bw, const float* __restrict__ WkT,
    const float* __restrict__ bk, const float* __restrict__ Wq,
    unsigned char* __restrict__ KWt) {
  const int m = blockIdx.x;      // 0..111
  const int c = threadIdx.x;     // 0..255
  __shared__ float knm[CC];
  __shared__ float red[4];

  float kv = 0.0f;
  if (m < CNB) {
    const float* bm = bw + (size_t)m * CC;   // broadcast reads
    float a0 = 0.f, a1 = 0.f, a2 = 0.f, a3 = 0.f;
    #pragma unroll 4
    for (int j = 0; j < CC; j += 4) {        // WkT reads coalesced over c
      a0 += bm[j + 0] * WkT[(size_t)(j + 0) * CC + c];
      a1 += bm[j + 1] * WkT[(size_t)(j + 1) * CC + c];
      a2 += bm[j + 2] * WkT[(size_t)(j + 2) * CC + c];
      a3 += bm[j + 3] * WkT[(size_t)(j + 3) * CC + c];
    }
    kv = (a0 + a1) + (a2 + a3) + bk[c];
  }
  float s = kv * kv;
  s += __shfl_xor(s, 1);  s += __shfl_xor(s, 2);  s += __shfl_xor(s, 4);
  s += __shfl_xor(s, 8);  s += __shfl_xor(s, 16); s += __shfl_xor(s, 32);
  const int wv = threadIdx.x >> 6, ln = threadIdx.x & 63;
  if (ln == 0) red[wv] = s;
  __syncthreads();
  const float tot = red[0] + red[1] + red[2] + red[3];
  const float rn = 1.0f / fmaxf(sqrtf(tot), EPSF);
  knm[c] = kv * rn;                 // rows m>=100 are all-zero (kv==0)
  __syncthreads();
  float acc0 = 0.f, acc1 = 0.f, acc2 = 0.f, acc3 = 0.f;
  const float* wq = Wq + c;
  #pragma unroll 4
  for (int cc = 0; cc < CC; cc += 4) {
    acc0 += knm[cc + 0] * wq[(size_t)(cc + 0) * CC];
    acc1 += knm[cc + 1] * wq[(size_t)(cc + 1) * CC];
    acc2 += knm[cc + 2] * wq[(size_t)(cc + 2) * CC];
    acc3 += knm[cc + 3] * wq[(size_t)(cc + 3) * CC];
  }
  const float kwv = (m < CNB) ? (acc0 + acc1) + (acc2 + acc3) : 0.0f;
  const int nt = m >> 4, l16 = m & 15, kc = c >> 5, quad = (c >> 3) & 3, j = c & 7;
  const int lane = quad * 16 + l16;
  const size_t byte = (size_t)nt * 8192 + kc * 1024 + lane * 16 + j * 2;
  *(uint16_t*)(KWt + byte) = (uint16_t)(unsigned short)f2bf(kwv);
}

// =========================== main ===========================
// 512 blocks (64 b x 8 tiles of 256 rows), 1024 threads = 16 waves (16 rows/wave).
// ALL B data (Wq8 fp8 64KB + KWt bf16 56KB = 120KB) staged into dynamic LDS
// ONCE (linear global_load_lds copy), ONE barrier, then the 23-tile stream runs
// with NO barriers — waves are independent ds_read->MFMA chains (kills the
// round-4 barrier-drain stall; L2 staging traffic 377MB -> 60MB).
// Q phase in fp8 (only feeds ||q||, error ~0.3% -> logit shift <=0.003, safe);
// S phase stays bf16 (fp8 would add ~0.05 absolute logit noise - unsafe).
// launch_bounds(1024,4): one block/CU (LDS-bound), needs <=128 regs/wave.
__global__ __launch_bounds__(1024, 4) void main_kernel(
    const float* __restrict__ X, const float* __restrict__ mask,
    const unsigned char* __restrict__ Wq8, const float* __restrict__ bq,
    const unsigned char* __restrict__ KWt,
    float* __restrict__ att_sum, float* __restrict__ x_sum, float* __restrict__ mask_sum) {
  extern __shared__ char smem[];   // [0,65536): fp8 Q tiles; [65536,122880): bf16 S tiles
  const int b    = blockIdx.x >> 3;
  const int tile = blockIdx.x & 7;
  const int n0   = tile * 256;
  const int tid  = threadIdx.x;
  const int wave = tid >> 6;
  const int lane = tid & 63;
  const int quad = lane >> 4;
  const int l16  = lane & 15;
  const int row0 = n0 + wave * 16;

  // ---- stage all 120 KB linearly: 120 chunks of 1KB over 16 waves ----
  for (int i = wave; i < 120; i += 16) {
    const char* src = (i < 64) ? (const char*)Wq8 + (size_t)i * 1024
                               : (const char*)KWt + (size_t)(i - 64) * 1024;
    __builtin_amdgcn_global_load_lds((gas_ptr)(src + lane * 16),
                                     (las_ptr)(smem + i * 1024), 16, 0, 0);
  }

  // ---- phase 1: X rows -> bf16 A-frags + fp8 A-frags (for Q phase) ----
  short8 a[8];
  long   a8[8];
  {
    const float* xr = X + ((size_t)b * CN + row0 + l16) * CC + quad * 8;
    #pragma unroll
    for (int kc = 0; kc < 8; ++kc) {
      const float4* p = (const float4*)(xr + kc * 32);
      float4 f0 = p[0], f1 = p[1];
      short8 t;
      t[0] = f2bf(f0.x); t[1] = f2bf(f0.y); t[2] = f2bf(f0.z); t[3] = f2bf(f0.w);
      t[4] = f2bf(f1.x); t[5] = f2bf(f1.y); t[6] = f2bf(f1.z); t[7] = f2bf(f1.w);
      a[kc] = t;
      int lo = __builtin_amdgcn_cvt_pk_fp8_f32(f0.x, f0.y, 0, false);
      lo     = __builtin_amdgcn_cvt_pk_fp8_f32(f0.z, f0.w, lo, true);
      int hi = __builtin_amdgcn_cvt_pk_fp8_f32(f1.x, f1.y, 0, false);
      hi     = __builtin_amdgcn_cvt_pk_fp8_f32(f1.z, f1.w, hi, true);
      a8[kc] = (long)(unsigned)lo | ((long)hi << 32);
    }
  }
  const float mval = mask[(size_t)b * CN + row0 + l16];

  // ---- branch 1 (fp32) right away while the X tile is L2-fresh ----
  {
    const int col = tid & 255, rg = tid >> 8;        // 4 row-groups of 64
    float acc = 0.0f;
    const float* xp = X + ((size_t)b * CN + n0 + rg * 64) * CC + col;
    const float* mp = mask + (size_t)b * CN + n0 + rg * 64;
    #pragma unroll 8
    for (int r = 0; r < 64; ++r)
      acc += mp[r] * xp[(size_t)r * CC];
    atomicAdd(&x_sum[b * CC + col], acc);
  }
  if (wave == 0) {
    float mv = 0.0f;
    #pragma unroll
    for (int i = 0; i < 4; ++i) mv += mask[(size_t)b * CN + n0 + i * 64 + lane];
    mv += __shfl_xor(mv, 1); mv += __shfl_xor(mv, 2); mv += __shfl_xor(mv, 4);
    mv += __shfl_xor(mv, 8); mv += __shfl_xor(mv, 16); mv += __shfl_xor(mv, 32);
    if (lane == 0) atomicAdd(&mask_sum[b], mv);
  }

  __syncthreads();   // the ONLY barrier: all B tiles resident in LDS

  // ---- Q phase: 16 fp8 tiles, row sum-of-squares only ----
  float sumsq[4] = {0.f, 0.f, 0.f, 0.f};
  for (int t = 0; t < 16; ++t) {
    floatx4 acc = {0.f, 0.f, 0.f, 0.f};
    const char* bp = smem + t * 4096 + lane * 16;
    #pragma unroll
    for (int kp = 0; kp < 4; ++kp) {
      long2v bf = *(const long2v*)(bp + kp * 1024);   // frags for kc=2kp, 2kp+1
      acc = __builtin_amdgcn_mfma_f32_16x16x32_fp8_fp8(a8[2 * kp],     bf[0], acc, 0, 0, 0);
      acc = __builtin_amdgcn_mfma_f32_16x16x32_fp8_fp8(a8[2 * kp + 1], bf[1], acc, 0, 0, 0);
    }
    const float bqv = bq[t * 16 + l16];
    #pragma unroll
    for (int r = 0; r < 4; ++r) {
      float q = acc[r] + bqv;
      sumsq[r] += q * q;
    }
  }
  float rnorm[4];
  #pragma unroll
  for (int r = 0; r < 4; ++r) {
    float s = sumsq[r];
    s += __shfl_xor(s, 1); s += __shfl_xor(s, 2);
    s += __shfl_xor(s, 4); s += __shfl_xor(s, 8);
    rnorm[r] = 1.0f / fmaxf(sqrtf(s), EPSF);   // norm commutes: applied to S logits
  }

  // ---- S phase: 7 bf16 tiles into sacc (static indexing) ----
  floatx4 sacc[7];
  #pragma unroll
  for (int nt = 0; nt < 7; ++nt) {
    floatx4 acc = {0.f, 0.f, 0.f, 0.f};
    const char* bp = smem + 65536 + nt * 8192 + lane * 16;
    #pragma unroll
    for (int kc = 0; kc < 8; ++kc) {
      short8 bf = *(const short8*)(bp + kc * 1024);
      acc = __builtin_amdgcn_mfma_f32_16x16x32_bf16(a[kc], bf, acc, 0, 0, 0);
    }
    sacc[nt] = acc;
  }

  // ---- softmax over m (|logit|<=1, no max-subtraction) + masked accumulation ----
  float mw[4];
  #pragma unroll
  for (int r = 0; r < 4; ++r)
    mw[r] = mask[(size_t)b * CN + row0 + quad * 4 + r];

  const bool v6 = (l16 < 4);               // tile 6 covers m=96..111; valid iff m<100
  float denom[4] = {0.f, 0.f, 0.f, 0.f};
  #pragma unroll
  for (int nt = 0; nt < 7; ++nt) {
    const bool v = (nt < 6) || v6;
    #pragma unroll
    for (int r = 0; r < 4; ++r)
      denom[r] += v ? __expf(sacc[nt][r] * rnorm[r]) : 0.0f;
  }
  float wr[4];
  #pragma unroll
  for (int r = 0; r < 4; ++r) {
    float s = denom[r];
    s += __shfl_xor(s, 1); s += __shfl_xor(s, 2);
    s += __shfl_xor(s, 4); s += __shfl_xor(s, 8);
    wr[r] = mw[r] / s;                      // fold mask weight and 1/denom
  }
  #pragma unroll
  for (int nt = 0; nt < 7; ++nt) {
    const bool v = (nt < 6) || v6;
    float contrib = 0.0f;
    #pragma unroll
    for (int r = 0; r < 4; ++r) {
      float e = v ? __expf(sacc[nt][r] * rnorm[r]) : 0.0f;
      contrib += e * wr[r];
    }
    contrib += __shfl_xor(contrib, 16);
    contrib += __shfl_xor(contrib, 32);     // sum this wave's 16 rows
    if (quad == 0)
      atomicAdd(&att_sum[b * CNBP + nt * 16 + l16], contrib);
  }
}

// =========================== final combine ===========================
__global__ __launch_bounds__(256) void final_kernel(
    const float* __restrict__ bw, const float* __restrict__ w_avg,
    const float* __restrict__ w_att,
    const float* __restrict__ att_sum, const float* __restrict__ x_sum,
    const float* __restrict__ mask_sum, float* __restrict__ out) {
  const int b = blockIdx.x, c = threadIdx.x;
  const float rd  = 1.0f / fmaxf(mask_sum[b], EPSF);
  const float wn1 = x_sum[b * CC + c] * rd * w_avg[c];
  float acc = 0.0f;
  #pragma unroll 10
  for (int m = 0; m < CNB; ++m)
    acc += att_sum[b * CNBP + m] * bw[(size_t)m * CC + c];
  const float wn2 = acc * rd;
  out[b * CC + c] = (wn1 + wn2 * w_att[c]) * 0.5f;
}

extern "C" void kernel_launch(void* const* d_in, const int* in_sizes, int n_in,
                              void* d_out, int out_size, void* d_ws, size_t ws_size,
                              hipStream_t stream) {
  const float* bw    = (const float*)d_in[0];
  const float* X     = (const float*)d_in[1];
  const float* mask  = (const float*)d_in[2];
  const float* Wq    = (const float*)d_in[3];
  const float* bq    = (const float*)d_in[4];
  const float* Wk    = (const float*)d_in[5];
  const float* bk    = (const float*)d_in[6];
  const float* w_avg = (const float*)d_in[7];
  const float* w_att = (const float*)d_in[8];
  float* out = (float*)d_out;

  char* ws = (char*)d_ws;
  unsigned char* Wq8 = (unsigned char*)(ws + 0);        //  65536 B (fp8 tiled)
  unsigned char* KWt = (unsigned char*)(ws + 65536);    //  57344 B (bf16 tiled)
  float* WkT         = (float*)(ws + 122880);           // 262144 B
  float* att_sum     = (float*)(ws + 385024);           //  28672 B (64 x 112)
  float* x_sum       = (float*)(ws + 413696);           //  65536 B (64 x 256)
  float* msum        = (float*)(ws + 479232);           //    256 B (64)

  hipMemsetAsync(ws + 385024, 0, 28672 + 65536 + 256, stream);

  static int lds_set = 0;
  hipFuncSetAttribute((const void*)main_kernel,
                      hipFuncAttributeMaxDynamicSharedMemorySize, 122880);
  (void)lds_set;

  prepA_kernel<<<256, 256, 0, stream>>>(Wq, Wk, Wq8, WkT);
  prepB_kernel<<<CNBP, 256, 0, stream>>>(bw, WkT, bk, Wq, KWt);
  main_kernel<<<512, 1024, 122880, stream>>>(X, mask, Wq8, bq, KWt, att_sum, x_sum, msum);
  final_kernel<<<CB, CC, 0, stream>>>(bw, w_avg, w_att, att_sum, x_sum, msum, out);
}